// Round 6
// baseline (554.386 us; speedup 1.0000x reference)
//
#include <hip/hip_runtime.h>
#include <math.h>

#define NLV 16
#define LOG2_T 19
#define T_SIZE (1u << LOG2_T)
#define T_MASK (T_SIZE - 1u)
#define P2 2654435761u
#define P3 805459861u
#define NBUCK 32768   // 32^3 Morton buckets

typedef float vf2 __attribute__((ext_vector_type(2)));
typedef float vf4 __attribute__((ext_vector_type(4)));

struct Scales { float s[NLV]; };

// ---------- Morton key (5 bits/axis) ----------
__device__ __forceinline__ unsigned mpart(unsigned v) {
    v = (v | (v << 8)) & 0x100Fu;
    v = (v | (v << 4)) & 0x10C3u;
    v = (v | (v << 2)) & 0x1249u;
    return v;
}
__device__ __forceinline__ unsigned mkey(float px, float py, float pz) {
    unsigned cx = (unsigned)(px * 32.f); cx = cx > 31u ? 31u : cx;
    unsigned cy = (unsigned)(py * 32.f); cy = cy > 31u ? 31u : cy;
    unsigned cz = (unsigned)(pz * 32.f); cz = cz > 31u ? 31u : cz;
    return mpart(cx) | (mpart(cy) << 1) | (mpart(cz) << 2);
}

// ---------- sort kernels ----------
__global__ __launch_bounds__(256) void zero_hist_kernel(unsigned* hist) {
    int i = blockIdx.x * 256 + threadIdx.x;
    if (i < NBUCK) hist[i] = 0u;
}

__global__ __launch_bounds__(256) void hist_kernel(
    const float* __restrict__ x, unsigned* __restrict__ hist, int N)
{
    const int q = blockIdx.x * 256 + threadIdx.x;
    const int i0 = q * 4;
    if (i0 >= N) return;
    if (i0 + 3 < N) {
        const vf4 A = *(const vf4*)(x + 12 * (size_t)q);
        const vf4 B = *(const vf4*)(x + 12 * (size_t)q + 4);
        const vf4 C = *(const vf4*)(x + 12 * (size_t)q + 8);
        const float px[4] = {A[0], A[3], B[2], C[1]};
        const float py[4] = {A[1], B[0], B[3], C[2]};
        const float pz[4] = {A[2], B[1], C[0], C[3]};
        #pragma unroll
        for (int k = 0; k < 4; ++k) atomicAdd(&hist[mkey(px[k], py[k], pz[k])], 1u);
    } else {
        for (int i = i0; i < N; ++i)
            atomicAdd(&hist[mkey(x[3*(size_t)i], x[3*(size_t)i+1], x[3*(size_t)i+2])], 1u);
    }
}

__global__ __launch_bounds__(1024) void scan_kernel(unsigned* hist) {
    __shared__ unsigned tot[1024];
    const int t = threadIdx.x;
    const unsigned base = (unsigned)t * 32u;
    unsigned loc[32];
    unsigned s = 0;
    #pragma unroll
    for (int k = 0; k < 32; ++k) { loc[k] = s; s += hist[base + k]; }
    tot[t] = s;
    __syncthreads();
    for (int off = 1; off < 1024; off <<= 1) {
        unsigned u = (t >= off) ? tot[t - off] : 0u;
        __syncthreads();
        tot[t] += u;
        __syncthreads();
    }
    const unsigned excl = tot[t] - s;
    #pragma unroll
    for (int k = 0; k < 32; ++k) hist[base + k] = excl + loc[k];
}

__global__ __launch_bounds__(256) void scatter_kernel(
    const float* __restrict__ x, unsigned* __restrict__ cursor,
    vf4* __restrict__ xs, int* __restrict__ perm, int N)
{
    const int q = blockIdx.x * 256 + threadIdx.x;
    const int i0 = q * 4;
    if (i0 >= N) return;
    if (i0 + 3 < N) {
        const vf4 A = *(const vf4*)(x + 12 * (size_t)q);
        const vf4 B = *(const vf4*)(x + 12 * (size_t)q + 4);
        const vf4 C = *(const vf4*)(x + 12 * (size_t)q + 8);
        const float px[4] = {A[0], A[3], B[2], C[1]};
        const float py[4] = {A[1], B[0], B[3], C[2]};
        const float pz[4] = {A[2], B[1], C[0], C[3]};
        #pragma unroll
        for (int k = 0; k < 4; ++k) {
            const unsigned key = mkey(px[k], py[k], pz[k]);
            const unsigned pos = atomicAdd(&cursor[key], 1u);
            vf4 v; v[0] = px[k]; v[1] = py[k]; v[2] = pz[k]; v[3] = 0.f;
            xs[pos] = v;
            perm[pos] = i0 + k;
        }
    } else {
        for (int i = i0; i < N; ++i) {
            const float px = x[3*(size_t)i], py = x[3*(size_t)i+1], pz = x[3*(size_t)i+2];
            const unsigned key = mkey(px, py, pz);
            const unsigned pos = atomicAdd(&cursor[key], 1u);
            vf4 v; v[0] = px; v[1] = py; v[2] = pz; v[3] = 0.f;
            xs[pos] = v;
            perm[pos] = i;
        }
    }
}

// ---------- encode ----------
// BYPASS=true: device-scope load (sc1) skips L1 allocation — for levels whose
// table working set thrashes the 32 KiB L1 (~1% hit rate, fill overhead).
template<bool BYPASS>
__device__ __forceinline__ void enc_level_t(
    float px, float py, float pz, float s, const float* __restrict__ tl,
    float& f0, float& f1)
{
    const float fx = px * s, fy = py * s, fz = pz * s;
    const float bx = floorf(fx), by = floorf(fy), bz = floorf(fz);
    const float rx = fx - bx, ry = fy - by, rz = fz - bz;
    const unsigned ix0 = (unsigned)bx, iy0 = (unsigned)by, iz0 = (unsigned)bz;
    const unsigned hx0 = ix0,      hx1 = ix0 + 1u;
    const unsigned hy0 = iy0 * P2, hy1 = (iy0 + 1u) * P2;
    const unsigned hz0 = iz0 * P3, hz1 = (iz0 + 1u) * P3;
    const float wx0 = 1.f - rx, wy0 = 1.f - ry, wz0 = 1.f - rz;
    f0 = 0.f; f1 = 0.f;
    #pragma unroll
    for (int c = 0; c < 8; ++c) {
        unsigned h = ((c & 4) ? hx1 : hx0) ^ ((c & 2) ? hy1 : hy0) ^ ((c & 1) ? hz1 : hz0);
        h &= T_MASK;
        vf2 f;
        if constexpr (BYPASS) {
            unsigned long long u = __hip_atomic_load(
                (const unsigned long long*)(tl + 2u * (size_t)h),
                __ATOMIC_RELAXED, __HIP_MEMORY_SCOPE_AGENT);
            union { unsigned long long u; vf2 f; } cv; cv.u = u; f = cv.f;
        } else {
            f = *(const vf2*)(tl + 2u * (size_t)h);
        }
        const float w = ((c & 4) ? rx : wx0) * ((c & 2) ? ry : wy0) * ((c & 1) ? rz : wz0);
        f0 += w * f[0];
        f1 += w * f[1];
    }
}

// Levels 0..4 fused (working sets co-resident in L2, L1-friendly after sort).
__global__ __launch_bounds__(256) void encode_coarse_kernel(
    const vf4* __restrict__ xs, const float* __restrict__ table,
    float* __restrict__ enc, int N, Scales sc)
{
    int i = blockIdx.x * 256 + threadIdx.x;
    if (i >= N) return;
    const vf4 p = xs[i];
    #pragma unroll
    for (int l = 0; l < 5; ++l) {
        float f0, f1;
        enc_level_t<false>(p[0], p[1], p[2], sc.s[l], table + (size_t)l * T_SIZE * 2u, f0, f1);
        vf2 v; v[0] = f0; v[1] = f1;
        *(vf2*)(enc + ((size_t)l * N + i) * 2u) = v;
    }
}

// One fine level per launch; 4 points per thread.
template<bool BYPASS>
__global__ __launch_bounds__(256) void encode_one_kernel(
    const vf4* __restrict__ xs, const float* __restrict__ tl, float s,
    float* __restrict__ encl, int N)
{
    const int i0 = blockIdx.x * 1024 + threadIdx.x;
    #pragma unroll
    for (int k = 0; k < 4; ++k) {
        const int i = i0 + k * 256;
        if (i < N) {
            const vf4 p = xs[i];
            float f0, f1;
            enc_level_t<BYPASS>(p[0], p[1], p[2], s, tl, f0, f1);
            vf2 v; v[0] = f0; v[1] = f1;
            *(vf2*)(encl + (size_t)i * 2u) = v;
        }
    }
}

// ---------- MLP: 512 pts/block in two 256-pt halves (17 KB LDS -> 8 blocks/CU),
// float2-pair accumulation (v_pk_fma_f32), LDS-staged cooperative store ----------
__global__ __launch_bounds__(256) void mlp_kernel(
    const float* __restrict__ enc, const int* __restrict__ perm,
    const float* __restrict__ W0, const float* __restrict__ b0,
    const float* __restrict__ W1, const float* __restrict__ b1,
    const float* __restrict__ W2, const float* __restrict__ b2,
    float* __restrict__ out, int N)
{
    __shared__ float st[256 * 17];   // 17408 B
    const int base = blockIdx.x * 512;
    const int t = threadIdx.x;

    #pragma unroll
    for (int q = 0; q < 2; ++q) {
        if (q) __syncthreads();              // st reuse hazard (uniform branch)
        const int i = base + q * 256 + t;
        if (i < N) {
            vf2 e2[16];
            #pragma unroll
            for (int l = 0; l < NLV; ++l)
                e2[l] = *(const vf2*)(enc + ((size_t)l * N + i) * 2u);

            vf2 a0v[8];
            #pragma unroll
            for (int j = 0; j < 16; ++j) {
                vf2 acc = {0.f, 0.f};
                #pragma unroll
                for (int l = 0; l < 16; ++l)
                    acc += e2[l] * *(const vf2*)(W0 + j * 32 + 2 * l);
                a0v[j >> 1][j & 1] = fmaxf(b0[j] + acc[0] + acc[1], 0.f);
            }
            vf2 a1v[8];
            #pragma unroll
            for (int j = 0; j < 16; ++j) {
                vf2 acc = {0.f, 0.f};
                #pragma unroll
                for (int k = 0; k < 8; ++k)
                    acc += a0v[k] * *(const vf2*)(W1 + j * 16 + 2 * k);
                a1v[j >> 1][j & 1] = fmaxf(b1[j] + acc[0] + acc[1], 0.f);
            }
            #pragma unroll
            for (int j = 0; j < 16; ++j) {
                vf2 acc = {0.f, 0.f};
                #pragma unroll
                for (int k = 0; k < 8; ++k)
                    acc += a1v[k] * *(const vf2*)(W2 + j * 16 + 2 * k);
                st[t * 17 + j] = b2[j] + acc[0] + acc[1];
            }
        }
        __syncthreads();

        // 4 lanes per point: 16 lines per store instr; line quarters merge in L2.
        const int c = t & 3;
        #pragma unroll
        for (int w = 0; w < 4; ++w) {
            const int p = (t >> 2) + w * 64;          // local row 0..255
            const int gi = base + q * 256 + p;
            if (gi < N) {
                const int dst = perm[gi];
                const vf4 v = *(const vf4*)&st[p * 17 + 4 * c];
                *(vf4*)(out + 16 * (size_t)dst + 4 * c) = v;
            }
        }
    }
}

// ---------- fallback paths ----------
__global__ __launch_bounds__(256) void encode_coarse_unsorted_kernel(
    const float* __restrict__ x, const float* __restrict__ table,
    float* __restrict__ enc, int N, Scales sc)
{
    int i = blockIdx.x * 256 + threadIdx.x;
    if (i >= N) return;
    const float px = x[3 * (size_t)i + 0];
    const float py = x[3 * (size_t)i + 1];
    const float pz = x[3 * (size_t)i + 2];
    #pragma unroll
    for (int l = 0; l < 5; ++l) {
        float f0, f1;
        enc_level_t<false>(px, py, pz, sc.s[l], table + (size_t)l * T_SIZE * 2u, f0, f1);
        vf2 v; v[0] = f0; v[1] = f1;
        *(vf2*)(enc + ((size_t)l * N + i) * 2u) = v;
    }
}
__global__ __launch_bounds__(256) void encode_one_unsorted_kernel(
    const float* __restrict__ x, const float* __restrict__ tl, float s,
    float* __restrict__ encl, int N)
{
    int i = blockIdx.x * 256 + threadIdx.x;
    if (i >= N) return;
    const float px = x[3 * (size_t)i + 0];
    const float py = x[3 * (size_t)i + 1];
    const float pz = x[3 * (size_t)i + 2];
    float f0, f1;
    enc_level_t<false>(px, py, pz, s, tl, f0, f1);
    vf2 v; v[0] = f0; v[1] = f1;
    *(vf2*)(encl + (size_t)i * 2u) = v;
}
__global__ __launch_bounds__(256) void mlp_noperm_kernel(
    const float* __restrict__ enc,
    const float* __restrict__ W0, const float* __restrict__ b0,
    const float* __restrict__ W1, const float* __restrict__ b1,
    const float* __restrict__ W2, const float* __restrict__ b2,
    float* __restrict__ out, int N)
{
    int i = blockIdx.x * 256 + threadIdx.x;
    if (i >= N) return;
    float e[32];
    #pragma unroll
    for (int l = 0; l < NLV; ++l) {
        vf2 v = *(const vf2*)(enc + ((size_t)l * N + i) * 2u);
        e[2 * l + 0] = v[0];
        e[2 * l + 1] = v[1];
    }
    float a0[16];
    #pragma unroll
    for (int j = 0; j < 16; ++j) {
        float s = b0[j];
        #pragma unroll
        for (int k = 0; k < 32; ++k) s += e[k] * W0[j * 32 + k];
        a0[j] = fmaxf(s, 0.f);
    }
    float a1[16];
    #pragma unroll
    for (int j = 0; j < 16; ++j) {
        float s = b1[j];
        #pragma unroll
        for (int k = 0; k < 16; ++k) s += a0[k] * W1[j * 16 + k];
        a1[j] = fmaxf(s, 0.f);
    }
    #pragma unroll
    for (int j = 0; j < 16; ++j) {
        float s = b2[j];
        #pragma unroll
        for (int k = 0; k < 16; ++k) s += a1[k] * W2[j * 16 + k];
        out[16 * (size_t)i + j] = s;
    }
}
__global__ __launch_bounds__(256) void tcnn_fused_kernel(
    const float* __restrict__ x, const float* __restrict__ table,
    const float* __restrict__ W0, const float* __restrict__ b0,
    const float* __restrict__ W1, const float* __restrict__ b1,
    const float* __restrict__ W2, const float* __restrict__ b2,
    float* __restrict__ out, int N, Scales sc)
{
    int i = blockIdx.x * blockDim.x + threadIdx.x;
    if (i >= N) return;
    const float px = x[3 * (size_t)i + 0];
    const float py = x[3 * (size_t)i + 1];
    const float pz = x[3 * (size_t)i + 2];
    float e[32];
    #pragma unroll
    for (int l = 0; l < NLV; ++l) {
        float f0, f1;
        enc_level_t<false>(px, py, pz, sc.s[l], table + (size_t)l * T_SIZE * 2u, f0, f1);
        e[2 * l] = f0; e[2 * l + 1] = f1;
    }
    float a0[16];
    #pragma unroll
    for (int j = 0; j < 16; ++j) {
        float s = b0[j];
        #pragma unroll
        for (int k = 0; k < 32; ++k) s += e[k] * W0[j * 32 + k];
        a0[j] = fmaxf(s, 0.f);
    }
    float a1[16];
    #pragma unroll
    for (int j = 0; j < 16; ++j) {
        float s = b1[j];
        #pragma unroll
        for (int k = 0; k < 16; ++k) s += a0[k] * W1[j * 16 + k];
        a1[j] = fmaxf(s, 0.f);
    }
    #pragma unroll
    for (int j = 0; j < 16; ++j) {
        float s = b2[j];
        #pragma unroll
        for (int k = 0; k < 16; ++k) s += a1[k] * W2[j * 16 + k];
        out[16 * (size_t)i + j] = s;
    }
}

extern "C" void kernel_launch(void* const* d_in, const int* in_sizes, int n_in,
                              void* d_out, int out_size, void* d_ws, size_t ws_size,
                              hipStream_t stream) {
    const float* x     = (const float*)d_in[0];
    const float* table = (const float*)d_in[1];
    const float* W0    = (const float*)d_in[2];
    const float* b0    = (const float*)d_in[3];
    const float* W1    = (const float*)d_in[4];
    const float* b1    = (const float*)d_in[5];
    const float* W2    = (const float*)d_in[6];
    const float* b2    = (const float*)d_in[7];
    float* out = (float*)d_out;

    const int N = in_sizes[0] / 3;

    Scales sc;
    const double pls = exp2(log2(2048.0 / 16.0) / 15.0);  // matches numpy double math
    for (int l = 0; l < NLV; ++l) sc.s[l] = (float)(16.0 * pow(pls, (double)l));

    const int block = 256;
    const int grid = (N + block - 1) / block;

    const size_t encB  = (size_t)N * 2u * NLV * sizeof(float);   // 128 MiB
    const size_t xsB   = (size_t)N * sizeof(float) * 4u;         //  16 MiB
    const size_t permB = (size_t)N * sizeof(int);                //   4 MiB
    const size_t histB = (size_t)NBUCK * sizeof(unsigned);

    if (ws_size >= encB + xsB + permB + histB) {
        float*    enc  = (float*)d_ws;
        vf4*      xs   = (vf4*)((char*)d_ws + encB);
        int*      perm = (int*)((char*)d_ws + encB + xsB);
        unsigned* hist = (unsigned*)((char*)d_ws + encB + xsB + permB);

        const int gridQ = (N + 1023) / 1024;   // 4 pts/thread kernels
        zero_hist_kernel<<<(NBUCK + 255) / 256, block, 0, stream>>>(hist);
        hist_kernel<<<gridQ, block, 0, stream>>>(x, hist, N);
        scan_kernel<<<1, 1024, 0, stream>>>(hist);
        scatter_kernel<<<gridQ, block, 0, stream>>>(x, hist, xs, perm, N);

        encode_coarse_kernel<<<grid, block, 0, stream>>>(xs, table, enc, N, sc);
        for (int l = 5; l < 8; ++l) {
            encode_one_kernel<false><<<gridQ, block, 0, stream>>>(
                xs, table + (size_t)l * T_SIZE * 2u, sc.s[l],
                enc + (size_t)l * (size_t)N * 2u, N);
        }
        for (int l = 8; l < NLV; ++l) {
            encode_one_kernel<true><<<gridQ, block, 0, stream>>>(
                xs, table + (size_t)l * T_SIZE * 2u, sc.s[l],
                enc + (size_t)l * (size_t)N * 2u, N);
        }
        const int gridM = (N + 511) / 512;     // 512 pts/block MLP
        mlp_kernel<<<gridM, block, 0, stream>>>(enc, perm, W0, b0, W1, b1, W2, b2, out, N);
    } else if (ws_size >= encB) {
        float* enc = (float*)d_ws;
        encode_coarse_unsorted_kernel<<<grid, block, 0, stream>>>(x, table, enc, N, sc);
        for (int l = 5; l < NLV; ++l) {
            encode_one_unsorted_kernel<<<grid, block, 0, stream>>>(
                x, table + (size_t)l * T_SIZE * 2u, sc.s[l],
                enc + (size_t)l * (size_t)N * 2u, N);
        }
        mlp_noperm_kernel<<<grid, block, 0, stream>>>(enc, W0, b0, W1, b1, W2, b2, out, N);
    } else {
        tcnn_fused_kernel<<<grid, block, 0, stream>>>(x, table, W0, b0, W1, b1, W2, b2,
                                                      out, N, sc);
    }
}

// Round 7
// 530.738 us; speedup vs baseline: 1.0446x; 1.0446x over previous
//
#include <hip/hip_runtime.h>
#include <math.h>

#define NLV 16
#define LOG2_T 19
#define T_SIZE (1u << LOG2_T)
#define T_MASK (T_SIZE - 1u)
#define P2 2654435761u
#define P3 805459861u
#define NBUCK 32768   // 32^3 Morton buckets

typedef float vf2 __attribute__((ext_vector_type(2)));
typedef float vf4 __attribute__((ext_vector_type(4)));

struct Scales { float s[NLV]; };

// ---------- Morton key (5 bits/axis) ----------
__device__ __forceinline__ unsigned mpart(unsigned v) {
    v = (v | (v << 8)) & 0x100Fu;
    v = (v | (v << 4)) & 0x10C3u;
    v = (v | (v << 2)) & 0x1249u;
    return v;
}
__device__ __forceinline__ unsigned mkey(float px, float py, float pz) {
    unsigned cx = (unsigned)(px * 32.f); cx = cx > 31u ? 31u : cx;
    unsigned cy = (unsigned)(py * 32.f); cy = cy > 31u ? 31u : cy;
    unsigned cz = (unsigned)(pz * 32.f); cz = cz > 31u ? 31u : cz;
    return mpart(cx) | (mpart(cy) << 1) | (mpart(cz) << 2);
}

// ---------- sort kernels ----------
__global__ __launch_bounds__(256) void zero_hist_kernel(unsigned* hist) {
    int i = blockIdx.x * 256 + threadIdx.x;
    if (i < NBUCK) hist[i] = 0u;
}

__global__ __launch_bounds__(256) void hist_kernel(
    const float* __restrict__ x, unsigned* __restrict__ hist, int N)
{
    const int q = blockIdx.x * 256 + threadIdx.x;
    const int i0 = q * 4;
    if (i0 >= N) return;
    if (i0 + 3 < N) {
        const vf4 A = *(const vf4*)(x + 12 * (size_t)q);
        const vf4 B = *(const vf4*)(x + 12 * (size_t)q + 4);
        const vf4 C = *(const vf4*)(x + 12 * (size_t)q + 8);
        const float px[4] = {A[0], A[3], B[2], C[1]};
        const float py[4] = {A[1], B[0], B[3], C[2]};
        const float pz[4] = {A[2], B[1], C[0], C[3]};
        #pragma unroll
        for (int k = 0; k < 4; ++k) atomicAdd(&hist[mkey(px[k], py[k], pz[k])], 1u);
    } else {
        for (int i = i0; i < N; ++i)
            atomicAdd(&hist[mkey(x[3*(size_t)i], x[3*(size_t)i+1], x[3*(size_t)i+2])], 1u);
    }
}

__global__ __launch_bounds__(1024) void scan_kernel(unsigned* hist) {
    __shared__ unsigned tot[1024];
    const int t = threadIdx.x;
    const unsigned base = (unsigned)t * 32u;
    unsigned loc[32];
    unsigned s = 0;
    #pragma unroll
    for (int k = 0; k < 32; ++k) { loc[k] = s; s += hist[base + k]; }
    tot[t] = s;
    __syncthreads();
    for (int off = 1; off < 1024; off <<= 1) {
        unsigned u = (t >= off) ? tot[t - off] : 0u;
        __syncthreads();
        tot[t] += u;
        __syncthreads();
    }
    const unsigned excl = tot[t] - s;
    #pragma unroll
    for (int k = 0; k < 32; ++k) hist[base + k] = excl + loc[k];
}

// One 16B record per point: {px,py,pz, bitcast(idx)} -> single line touch.
__global__ __launch_bounds__(256) void scatter_kernel(
    const float* __restrict__ x, unsigned* __restrict__ cursor,
    vf4* __restrict__ xs, int N)
{
    const int q = blockIdx.x * 256 + threadIdx.x;
    const int i0 = q * 4;
    if (i0 >= N) return;
    if (i0 + 3 < N) {
        const vf4 A = *(const vf4*)(x + 12 * (size_t)q);
        const vf4 B = *(const vf4*)(x + 12 * (size_t)q + 4);
        const vf4 C = *(const vf4*)(x + 12 * (size_t)q + 8);
        const float px[4] = {A[0], A[3], B[2], C[1]};
        const float py[4] = {A[1], B[0], B[3], C[2]};
        const float pz[4] = {A[2], B[1], C[0], C[3]};
        #pragma unroll
        for (int k = 0; k < 4; ++k) {
            const unsigned key = mkey(px[k], py[k], pz[k]);
            const unsigned pos = atomicAdd(&cursor[key], 1u);
            vf4 v; v[0] = px[k]; v[1] = py[k]; v[2] = pz[k]; v[3] = __int_as_float(i0 + k);
            xs[pos] = v;
        }
    } else {
        for (int i = i0; i < N; ++i) {
            const float px = x[3*(size_t)i], py = x[3*(size_t)i+1], pz = x[3*(size_t)i+2];
            const unsigned key = mkey(px, py, pz);
            const unsigned pos = atomicAdd(&cursor[key], 1u);
            vf4 v; v[0] = px; v[1] = py; v[2] = pz; v[3] = __int_as_float(i);
            xs[pos] = v;
        }
    }
}

// ---------- encode ----------
__device__ __forceinline__ void enc_level(
    float px, float py, float pz, float s, const float* __restrict__ tl,
    float& f0, float& f1)
{
    const float fx = px * s, fy = py * s, fz = pz * s;
    const float bx = floorf(fx), by = floorf(fy), bz = floorf(fz);
    const float rx = fx - bx, ry = fy - by, rz = fz - bz;
    const unsigned ix0 = (unsigned)bx, iy0 = (unsigned)by, iz0 = (unsigned)bz;
    const unsigned hx0 = ix0,      hx1 = ix0 + 1u;
    const unsigned hy0 = iy0 * P2, hy1 = (iy0 + 1u) * P2;
    const unsigned hz0 = iz0 * P3, hz1 = (iz0 + 1u) * P3;
    const float wx0 = 1.f - rx, wy0 = 1.f - ry, wz0 = 1.f - rz;
    f0 = 0.f; f1 = 0.f;
    #pragma unroll
    for (int c = 0; c < 8; ++c) {
        unsigned h = ((c & 4) ? hx1 : hx0) ^ ((c & 2) ? hy1 : hy0) ^ ((c & 1) ? hz1 : hz0);
        h &= T_MASK;
        const vf2 f = *(const vf2*)(tl + 2u * (size_t)h);
        const float w = ((c & 4) ? rx : wx0) * ((c & 2) ? ry : wy0) * ((c & 1) ? rz : wz0);
        f0 += w * f[0];
        f1 += w * f[1];
    }
}

// Levels 0..4 fused (working sets co-resident in L2, L1-friendly after sort).
__global__ __launch_bounds__(256) void encode_coarse_kernel(
    const vf4* __restrict__ xs, const float* __restrict__ table,
    float* __restrict__ enc, int N, Scales sc)
{
    int i = blockIdx.x * 256 + threadIdx.x;
    if (i >= N) return;
    const vf4 p = xs[i];
    #pragma unroll
    for (int l = 0; l < 5; ++l) {
        float f0, f1;
        enc_level(p[0], p[1], p[2], sc.s[l], table + (size_t)l * T_SIZE * 2u, f0, f1);
        vf2 v; v[0] = f0; v[1] = f1;
        *(vf2*)(enc + ((size_t)l * N + i) * 2u) = v;
    }
}

// One fine level per launch; 4 points/thread; LVL tag -> per-level rocprof rows.
template<int LVL>
__global__ __launch_bounds__(256) void encode_fine_kernel(
    const vf4* __restrict__ xs, const float* __restrict__ tl, float s,
    float* __restrict__ encl, int N)
{
    const int i0 = blockIdx.x * 1024 + threadIdx.x;
    #pragma unroll
    for (int k = 0; k < 4; ++k) {
        const int i = i0 + k * 256;
        if (i < N) {
            const vf4 p = xs[i];
            float f0, f1;
            enc_level(p[0], p[1], p[2], s, tl, f0, f1);
            vf2 v; v[0] = f0; v[1] = f1;
            *(vf2*)(encl + (size_t)i * 2u) = v;
        }
    }
}

// ---------- MLP: 512 pts/block in two 256-pt halves (17 KB LDS -> 8 blocks/CU),
// float2-pair accumulation, LDS-staged cooperative NT store ----------
__global__ __launch_bounds__(256) void mlp_kernel(
    const float* __restrict__ enc, const vf4* __restrict__ xs,
    const float* __restrict__ W0, const float* __restrict__ b0,
    const float* __restrict__ W1, const float* __restrict__ b1,
    const float* __restrict__ W2, const float* __restrict__ b2,
    float* __restrict__ out, int N)
{
    __shared__ float st[256 * 17];   // 17408 B
    const int base = blockIdx.x * 512;
    const int t = threadIdx.x;
    const float* xsf = (const float*)xs;

    #pragma unroll
    for (int q = 0; q < 2; ++q) {
        if (q) __syncthreads();              // st reuse hazard (uniform branch)
        const int i = base + q * 256 + t;
        if (i < N) {
            vf2 e2[16];
            #pragma unroll
            for (int l = 0; l < NLV; ++l)
                e2[l] = *(const vf2*)(enc + ((size_t)l * N + i) * 2u);

            vf2 a0v[8];
            #pragma unroll
            for (int j = 0; j < 16; ++j) {
                vf2 acc = {0.f, 0.f};
                #pragma unroll
                for (int l = 0; l < 16; ++l)
                    acc += e2[l] * *(const vf2*)(W0 + j * 32 + 2 * l);
                a0v[j >> 1][j & 1] = fmaxf(b0[j] + acc[0] + acc[1], 0.f);
            }
            vf2 a1v[8];
            #pragma unroll
            for (int j = 0; j < 16; ++j) {
                vf2 acc = {0.f, 0.f};
                #pragma unroll
                for (int k = 0; k < 8; ++k)
                    acc += a0v[k] * *(const vf2*)(W1 + j * 16 + 2 * k);
                a1v[j >> 1][j & 1] = fmaxf(b1[j] + acc[0] + acc[1], 0.f);
            }
            #pragma unroll
            for (int j = 0; j < 16; ++j) {
                vf2 acc = {0.f, 0.f};
                #pragma unroll
                for (int k = 0; k < 8; ++k)
                    acc += a1v[k] * *(const vf2*)(W2 + j * 16 + 2 * k);
                st[t * 17 + j] = b2[j] + acc[0] + acc[1];
            }
        }
        __syncthreads();

        // 4 lanes per point; the 4 x 16B quarters of each output line coalesce
        // into one full-line NT write (no L2 allocation, out is never re-read).
        const int c = t & 3;
        #pragma unroll
        for (int w = 0; w < 4; ++w) {
            const int p = (t >> 2) + w * 64;          // local row 0..255
            const int gi = base + q * 256 + p;
            if (gi < N) {
                const int dst = __float_as_int(xsf[4 * (size_t)gi + 3]);
                const vf4 v = *(const vf4*)&st[p * 17 + 4 * c];
                __builtin_nontemporal_store(v, (vf4*)(out + 16 * (size_t)dst + 4 * c));
            }
        }
    }
}

// ---------- fallback paths ----------
__global__ __launch_bounds__(256) void encode_coarse_unsorted_kernel(
    const float* __restrict__ x, const float* __restrict__ table,
    float* __restrict__ enc, int N, Scales sc)
{
    int i = blockIdx.x * 256 + threadIdx.x;
    if (i >= N) return;
    const float px = x[3 * (size_t)i + 0];
    const float py = x[3 * (size_t)i + 1];
    const float pz = x[3 * (size_t)i + 2];
    #pragma unroll
    for (int l = 0; l < 5; ++l) {
        float f0, f1;
        enc_level(px, py, pz, sc.s[l], table + (size_t)l * T_SIZE * 2u, f0, f1);
        vf2 v; v[0] = f0; v[1] = f1;
        *(vf2*)(enc + ((size_t)l * N + i) * 2u) = v;
    }
}
__global__ __launch_bounds__(256) void encode_one_unsorted_kernel(
    const float* __restrict__ x, const float* __restrict__ tl, float s,
    float* __restrict__ encl, int N)
{
    int i = blockIdx.x * 256 + threadIdx.x;
    if (i >= N) return;
    const float px = x[3 * (size_t)i + 0];
    const float py = x[3 * (size_t)i + 1];
    const float pz = x[3 * (size_t)i + 2];
    float f0, f1;
    enc_level(px, py, pz, s, tl, f0, f1);
    vf2 v; v[0] = f0; v[1] = f1;
    *(vf2*)(encl + (size_t)i * 2u) = v;
}
__global__ __launch_bounds__(256) void mlp_noperm_kernel(
    const float* __restrict__ enc,
    const float* __restrict__ W0, const float* __restrict__ b0,
    const float* __restrict__ W1, const float* __restrict__ b1,
    const float* __restrict__ W2, const float* __restrict__ b2,
    float* __restrict__ out, int N)
{
    int i = blockIdx.x * 256 + threadIdx.x;
    if (i >= N) return;
    float e[32];
    #pragma unroll
    for (int l = 0; l < NLV; ++l) {
        vf2 v = *(const vf2*)(enc + ((size_t)l * N + i) * 2u);
        e[2 * l + 0] = v[0];
        e[2 * l + 1] = v[1];
    }
    float a0[16];
    #pragma unroll
    for (int j = 0; j < 16; ++j) {
        float s = b0[j];
        #pragma unroll
        for (int k = 0; k < 32; ++k) s += e[k] * W0[j * 32 + k];
        a0[j] = fmaxf(s, 0.f);
    }
    float a1[16];
    #pragma unroll
    for (int j = 0; j < 16; ++j) {
        float s = b1[j];
        #pragma unroll
        for (int k = 0; k < 16; ++k) s += a0[k] * W1[j * 16 + k];
        a1[j] = fmaxf(s, 0.f);
    }
    #pragma unroll
    for (int j = 0; j < 16; ++j) {
        float s = b2[j];
        #pragma unroll
        for (int k = 0; k < 16; ++k) s += a1[k] * W2[j * 16 + k];
        out[16 * (size_t)i + j] = s;
    }
}
__global__ __launch_bounds__(256) void tcnn_fused_kernel(
    const float* __restrict__ x, const float* __restrict__ table,
    const float* __restrict__ W0, const float* __restrict__ b0,
    const float* __restrict__ W1, const float* __restrict__ b1,
    const float* __restrict__ W2, const float* __restrict__ b2,
    float* __restrict__ out, int N, Scales sc)
{
    int i = blockIdx.x * blockDim.x + threadIdx.x;
    if (i >= N) return;
    const float px = x[3 * (size_t)i + 0];
    const float py = x[3 * (size_t)i + 1];
    const float pz = x[3 * (size_t)i + 2];
    float e[32];
    #pragma unroll
    for (int l = 0; l < NLV; ++l) {
        float f0, f1;
        enc_level(px, py, pz, sc.s[l], table + (size_t)l * T_SIZE * 2u, f0, f1);
        e[2 * l] = f0; e[2 * l + 1] = f1;
    }
    float a0[16];
    #pragma unroll
    for (int j = 0; j < 16; ++j) {
        float s = b0[j];
        #pragma unroll
        for (int k = 0; k < 32; ++k) s += e[k] * W0[j * 32 + k];
        a0[j] = fmaxf(s, 0.f);
    }
    float a1[16];
    #pragma unroll
    for (int j = 0; j < 16; ++j) {
        float s = b1[j];
        #pragma unroll
        for (int k = 0; k < 16; ++k) s += a0[k] * W1[j * 16 + k];
        a1[j] = fmaxf(s, 0.f);
    }
    #pragma unroll
    for (int j = 0; j < 16; ++j) {
        float s = b2[j];
        #pragma unroll
        for (int k = 0; k < 16; ++k) s += a1[k] * W2[j * 16 + k];
        out[16 * (size_t)i + j] = s;
    }
}

extern "C" void kernel_launch(void* const* d_in, const int* in_sizes, int n_in,
                              void* d_out, int out_size, void* d_ws, size_t ws_size,
                              hipStream_t stream) {
    const float* x     = (const float*)d_in[0];
    const float* table = (const float*)d_in[1];
    const float* W0    = (const float*)d_in[2];
    const float* b0    = (const float*)d_in[3];
    const float* W1    = (const float*)d_in[4];
    const float* b1    = (const float*)d_in[5];
    const float* W2    = (const float*)d_in[6];
    const float* b2    = (const float*)d_in[7];
    float* out = (float*)d_out;

    const int N = in_sizes[0] / 3;

    Scales sc;
    const double pls = exp2(log2(2048.0 / 16.0) / 15.0);  // matches numpy double math
    for (int l = 0; l < NLV; ++l) sc.s[l] = (float)(16.0 * pow(pls, (double)l));

    const int block = 256;
    const int grid = (N + block - 1) / block;

    const size_t encB  = (size_t)N * 2u * NLV * sizeof(float);   // 128 MiB
    const size_t xsB   = (size_t)N * sizeof(float) * 4u;         //  16 MiB
    const size_t histB = (size_t)NBUCK * sizeof(unsigned);

    if (ws_size >= encB + xsB + histB) {
        float*    enc  = (float*)d_ws;
        vf4*      xs   = (vf4*)((char*)d_ws + encB);
        unsigned* hist = (unsigned*)((char*)d_ws + encB + xsB);

        const int gridQ = (N + 1023) / 1024;   // 4 pts/thread kernels
        zero_hist_kernel<<<(NBUCK + 255) / 256, block, 0, stream>>>(hist);
        hist_kernel<<<gridQ, block, 0, stream>>>(x, hist, N);
        scan_kernel<<<1, 1024, 0, stream>>>(hist);
        scatter_kernel<<<gridQ, block, 0, stream>>>(x, hist, xs, N);

        encode_coarse_kernel<<<grid, block, 0, stream>>>(xs, table, enc, N, sc);

        #define LAUNCH_FINE(L) \
            encode_fine_kernel<L><<<gridQ, block, 0, stream>>>( \
                xs, table + (size_t)(L) * T_SIZE * 2u, sc.s[(L)], \
                enc + (size_t)(L) * (size_t)N * 2u, N)
        LAUNCH_FINE(5);  LAUNCH_FINE(6);  LAUNCH_FINE(7);  LAUNCH_FINE(8);
        LAUNCH_FINE(9);  LAUNCH_FINE(10); LAUNCH_FINE(11); LAUNCH_FINE(12);
        LAUNCH_FINE(13); LAUNCH_FINE(14); LAUNCH_FINE(15);
        #undef LAUNCH_FINE

        const int gridM = (N + 511) / 512;     // 512 pts/block MLP
        mlp_kernel<<<gridM, block, 0, stream>>>(enc, xs, W0, b0, W1, b1, W2, b2, out, N);
    } else if (ws_size >= encB) {
        float* enc = (float*)d_ws;
        encode_coarse_unsorted_kernel<<<grid, block, 0, stream>>>(x, table, enc, N, sc);
        for (int l = 5; l < NLV; ++l) {
            encode_one_unsorted_kernel<<<grid, block, 0, stream>>>(
                x, table + (size_t)l * T_SIZE * 2u, sc.s[l],
                enc + (size_t)l * (size_t)N * 2u, N);
        }
        mlp_noperm_kernel<<<grid, block, 0, stream>>>(enc, W0, b0, W1, b1, W2, b2, out, N);
    } else {
        tcnn_fused_kernel<<<grid, block, 0, stream>>>(x, table, W0, b0, W1, b1, W2, b2,
                                                      out, N, sc);
    }
}

// Round 8
// 529.870 us; speedup vs baseline: 1.0463x; 1.0016x over previous
//
#include <hip/hip_runtime.h>
#include <math.h>

#define NLV 16
#define LOG2_T 19
#define T_SIZE (1u << LOG2_T)
#define T_MASK (T_SIZE - 1u)
#define P2 2654435761u
#define P3 805459861u
#define NBUCK 32768   // 32^3 Morton buckets

typedef float vf2 __attribute__((ext_vector_type(2)));
typedef float vf4 __attribute__((ext_vector_type(4)));

struct Scales { float s[NLV]; };

// ---------- Morton key (5 bits/axis) ----------
__device__ __forceinline__ unsigned mpart(unsigned v) {
    v = (v | (v << 8)) & 0x100Fu;
    v = (v | (v << 4)) & 0x10C3u;
    v = (v | (v << 2)) & 0x1249u;
    return v;
}
__device__ __forceinline__ unsigned mkey(float px, float py, float pz) {
    unsigned cx = (unsigned)(px * 32.f); cx = cx > 31u ? 31u : cx;
    unsigned cy = (unsigned)(py * 32.f); cy = cy > 31u ? 31u : cy;
    unsigned cz = (unsigned)(pz * 32.f); cz = cz > 31u ? 31u : cz;
    return mpart(cx) | (mpart(cy) << 1) | (mpart(cz) << 2);
}

// ---------- sort kernels (1 pt/thread: latency-bound, maximize wave count) ----------
__global__ __launch_bounds__(256) void zero_hist_kernel(unsigned* hist) {
    int i = blockIdx.x * 256 + threadIdx.x;
    if (i < NBUCK) hist[i] = 0u;
}

__global__ __launch_bounds__(256) void hist_kernel(
    const float* __restrict__ x, unsigned* __restrict__ hist, int N)
{
    const int i = blockIdx.x * 256 + threadIdx.x;
    if (i >= N) return;
    const float px = x[3 * (size_t)i + 0];
    const float py = x[3 * (size_t)i + 1];
    const float pz = x[3 * (size_t)i + 2];
    atomicAdd(&hist[mkey(px, py, pz)], 1u);
}

__global__ __launch_bounds__(1024) void scan_kernel(unsigned* hist) {
    __shared__ unsigned tot[1024];
    const int t = threadIdx.x;
    const unsigned base = (unsigned)t * 32u;
    unsigned loc[32];
    unsigned s = 0;
    #pragma unroll
    for (int k = 0; k < 32; ++k) { loc[k] = s; s += hist[base + k]; }
    tot[t] = s;
    __syncthreads();
    for (int off = 1; off < 1024; off <<= 1) {
        unsigned u = (t >= off) ? tot[t - off] : 0u;
        __syncthreads();
        tot[t] += u;
        __syncthreads();
    }
    const unsigned excl = tot[t] - s;
    #pragma unroll
    for (int k = 0; k < 32; ++k) hist[base + k] = excl + loc[k];
}

// One 16B record per point: {px,py,pz, bitcast(idx)} -> single line touch.
__global__ __launch_bounds__(256) void scatter_kernel(
    const float* __restrict__ x, unsigned* __restrict__ cursor,
    vf4* __restrict__ xs, int N)
{
    const int i = blockIdx.x * 256 + threadIdx.x;
    if (i >= N) return;
    const float px = x[3 * (size_t)i + 0];
    const float py = x[3 * (size_t)i + 1];
    const float pz = x[3 * (size_t)i + 2];
    const unsigned key = mkey(px, py, pz);
    const unsigned pos = atomicAdd(&cursor[key], 1u);
    vf4 v; v[0] = px; v[1] = py; v[2] = pz; v[3] = __int_as_float(i);
    xs[pos] = v;
}

// ---------- encode ----------
__device__ __forceinline__ void enc_level(
    float px, float py, float pz, float s, const float* __restrict__ tl,
    float& f0, float& f1)
{
    const float fx = px * s, fy = py * s, fz = pz * s;
    const float bx = floorf(fx), by = floorf(fy), bz = floorf(fz);
    const float rx = fx - bx, ry = fy - by, rz = fz - bz;
    const unsigned ix0 = (unsigned)bx, iy0 = (unsigned)by, iz0 = (unsigned)bz;
    const unsigned hx0 = ix0,      hx1 = ix0 + 1u;
    const unsigned hy0 = iy0 * P2, hy1 = (iy0 + 1u) * P2;
    const unsigned hz0 = iz0 * P3, hz1 = (iz0 + 1u) * P3;
    const float wx0 = 1.f - rx, wy0 = 1.f - ry, wz0 = 1.f - rz;
    f0 = 0.f; f1 = 0.f;
    #pragma unroll
    for (int c = 0; c < 8; ++c) {
        unsigned h = ((c & 4) ? hx1 : hx0) ^ ((c & 2) ? hy1 : hy0) ^ ((c & 1) ? hz1 : hz0);
        h &= T_MASK;
        const vf2 f = *(const vf2*)(tl + 2u * (size_t)h);
        const float w = ((c & 4) ? rx : wx0) * ((c & 2) ? ry : wy0) * ((c & 1) ? rz : wz0);
        f0 += w * f[0];
        f1 += w * f[1];
    }
}

// Levels 0..4 fused (working sets co-resident in L2, L1-friendly after sort).
__global__ __launch_bounds__(256) void encode_coarse_kernel(
    const vf4* __restrict__ xs, const float* __restrict__ table,
    float* __restrict__ enc, int N, Scales sc)
{
    int i = blockIdx.x * 256 + threadIdx.x;
    if (i >= N) return;
    const vf4 p = xs[i];
    #pragma unroll
    for (int l = 0; l < 5; ++l) {
        float f0, f1;
        enc_level(p[0], p[1], p[2], sc.s[l], table + (size_t)l * T_SIZE * 2u, f0, f1);
        vf2 v; v[0] = f0; v[1] = f1;
        *(vf2*)(enc + ((size_t)l * N + i) * 2u) = v;
    }
}

// One fine level per launch; 4 points/thread; LVL tag -> per-level rocprof rows.
template<int LVL>
__global__ __launch_bounds__(256) void encode_fine_kernel(
    const vf4* __restrict__ xs, const float* __restrict__ tl, float s,
    float* __restrict__ encl, int N)
{
    const int i0 = blockIdx.x * 1024 + threadIdx.x;
    #pragma unroll
    for (int k = 0; k < 4; ++k) {
        const int i = i0 + k * 256;
        if (i < N) {
            const vf4 p = xs[i];
            float f0, f1;
            enc_level(p[0], p[1], p[2], s, tl, f0, f1);
            vf2 v; v[0] = f0; v[1] = f1;
            *(vf2*)(encl + (size_t)i * 2u) = v;
        }
    }
}

// ---------- MLP: 512 pts/block in two 256-pt halves (17 KB LDS -> 8 blocks/CU),
// float2-pair accumulation, LDS-staged cooperative NT store ----------
__global__ __launch_bounds__(256) void mlp_kernel(
    const float* __restrict__ enc, const vf4* __restrict__ xs,
    const float* __restrict__ W0, const float* __restrict__ b0,
    const float* __restrict__ W1, const float* __restrict__ b1,
    const float* __restrict__ W2, const float* __restrict__ b2,
    float* __restrict__ out, int N)
{
    __shared__ float st[256 * 17];   // 17408 B
    const int base = blockIdx.x * 512;
    const int t = threadIdx.x;
    const float* xsf = (const float*)xs;

    #pragma unroll
    for (int q = 0; q < 2; ++q) {
        if (q) __syncthreads();              // st reuse hazard (uniform branch)
        const int i = base + q * 256 + t;
        if (i < N) {
            vf2 e2[16];
            #pragma unroll
            for (int l = 0; l < NLV; ++l)
                e2[l] = *(const vf2*)(enc + ((size_t)l * N + i) * 2u);

            vf2 a0v[8];
            #pragma unroll
            for (int j = 0; j < 16; ++j) {
                vf2 acc = {0.f, 0.f};
                #pragma unroll
                for (int l = 0; l < 16; ++l)
                    acc += e2[l] * *(const vf2*)(W0 + j * 32 + 2 * l);
                a0v[j >> 1][j & 1] = fmaxf(b0[j] + acc[0] + acc[1], 0.f);
            }
            vf2 a1v[8];
            #pragma unroll
            for (int j = 0; j < 16; ++j) {
                vf2 acc = {0.f, 0.f};
                #pragma unroll
                for (int k = 0; k < 8; ++k)
                    acc += a0v[k] * *(const vf2*)(W1 + j * 16 + 2 * k);
                a1v[j >> 1][j & 1] = fmaxf(b1[j] + acc[0] + acc[1], 0.f);
            }
            #pragma unroll
            for (int j = 0; j < 16; ++j) {
                vf2 acc = {0.f, 0.f};
                #pragma unroll
                for (int k = 0; k < 8; ++k)
                    acc += a1v[k] * *(const vf2*)(W2 + j * 16 + 2 * k);
                st[t * 17 + j] = b2[j] + acc[0] + acc[1];
            }
        }
        __syncthreads();

        // 4 lanes per point; the 4 x 16B quarters of each output line coalesce
        // into one full-line NT write (no L2 allocation, out is never re-read).
        const int c = t & 3;
        #pragma unroll
        for (int w = 0; w < 4; ++w) {
            const int p = (t >> 2) + w * 64;          // local row 0..255
            const int gi = base + q * 256 + p;
            if (gi < N) {
                const int dst = __float_as_int(xsf[4 * (size_t)gi + 3]);
                const vf4 v = *(const vf4*)&st[p * 17 + 4 * c];
                __builtin_nontemporal_store(v, (vf4*)(out + 16 * (size_t)dst + 4 * c));
            }
        }
    }
}

// ---------- fallback paths ----------
__global__ __launch_bounds__(256) void encode_coarse_unsorted_kernel(
    const float* __restrict__ x, const float* __restrict__ table,
    float* __restrict__ enc, int N, Scales sc)
{
    int i = blockIdx.x * 256 + threadIdx.x;
    if (i >= N) return;
    const float px = x[3 * (size_t)i + 0];
    const float py = x[3 * (size_t)i + 1];
    const float pz = x[3 * (size_t)i + 2];
    #pragma unroll
    for (int l = 0; l < 5; ++l) {
        float f0, f1;
        enc_level(px, py, pz, sc.s[l], table + (size_t)l * T_SIZE * 2u, f0, f1);
        vf2 v; v[0] = f0; v[1] = f1;
        *(vf2*)(enc + ((size_t)l * N + i) * 2u) = v;
    }
}
__global__ __launch_bounds__(256) void encode_one_unsorted_kernel(
    const float* __restrict__ x, const float* __restrict__ tl, float s,
    float* __restrict__ encl, int N)
{
    int i = blockIdx.x * 256 + threadIdx.x;
    if (i >= N) return;
    const float px = x[3 * (size_t)i + 0];
    const float py = x[3 * (size_t)i + 1];
    const float pz = x[3 * (size_t)i + 2];
    float f0, f1;
    enc_level(px, py, pz, s, tl, f0, f1);
    vf2 v; v[0] = f0; v[1] = f1;
    *(vf2*)(encl + (size_t)i * 2u) = v;
}
__global__ __launch_bounds__(256) void mlp_noperm_kernel(
    const float* __restrict__ enc,
    const float* __restrict__ W0, const float* __restrict__ b0,
    const float* __restrict__ W1, const float* __restrict__ b1,
    const float* __restrict__ W2, const float* __restrict__ b2,
    float* __restrict__ out, int N)
{
    int i = blockIdx.x * 256 + threadIdx.x;
    if (i >= N) return;
    float e[32];
    #pragma unroll
    for (int l = 0; l < NLV; ++l) {
        vf2 v = *(const vf2*)(enc + ((size_t)l * N + i) * 2u);
        e[2 * l + 0] = v[0];
        e[2 * l + 1] = v[1];
    }
    float a0[16];
    #pragma unroll
    for (int j = 0; j < 16; ++j) {
        float s = b0[j];
        #pragma unroll
        for (int k = 0; k < 32; ++k) s += e[k] * W0[j * 32 + k];
        a0[j] = fmaxf(s, 0.f);
    }
    float a1[16];
    #pragma unroll
    for (int j = 0; j < 16; ++j) {
        float s = b1[j];
        #pragma unroll
        for (int k = 0; k < 16; ++k) s += a0[k] * W1[j * 16 + k];
        a1[j] = fmaxf(s, 0.f);
    }
    #pragma unroll
    for (int j = 0; j < 16; ++j) {
        float s = b2[j];
        #pragma unroll
        for (int k = 0; k < 16; ++k) s += a1[k] * W2[j * 16 + k];
        out[16 * (size_t)i + j] = s;
    }
}
__global__ __launch_bounds__(256) void tcnn_fused_kernel(
    const float* __restrict__ x, const float* __restrict__ table,
    const float* __restrict__ W0, const float* __restrict__ b0,
    const float* __restrict__ W1, const float* __restrict__ b1,
    const float* __restrict__ W2, const float* __restrict__ b2,
    float* __restrict__ out, int N, Scales sc)
{
    int i = blockIdx.x * blockDim.x + threadIdx.x;
    if (i >= N) return;
    const float px = x[3 * (size_t)i + 0];
    const float py = x[3 * (size_t)i + 1];
    const float pz = x[3 * (size_t)i + 2];
    float e[32];
    #pragma unroll
    for (int l = 0; l < NLV; ++l) {
        float f0, f1;
        enc_level(px, py, pz, sc.s[l], table + (size_t)l * T_SIZE * 2u, f0, f1);
        e[2 * l] = f0; e[2 * l + 1] = f1;
    }
    float a0[16];
    #pragma unroll
    for (int j = 0; j < 16; ++j) {
        float s = b0[j];
        #pragma unroll
        for (int k = 0; k < 32; ++k) s += e[k] * W0[j * 32 + k];
        a0[j] = fmaxf(s, 0.f);
    }
    float a1[16];
    #pragma unroll
    for (int j = 0; j < 16; ++j) {
        float s = b1[j];
        #pragma unroll
        for (int k = 0; k < 16; ++k) s += a0[k] * W1[j * 16 + k];
        a1[j] = fmaxf(s, 0.f);
    }
    #pragma unroll
    for (int j = 0; j < 16; ++j) {
        float s = b2[j];
        #pragma unroll
        for (int k = 0; k < 16; ++k) s += a1[k] * W2[j * 16 + k];
        out[16 * (size_t)i + j] = s;
    }
}

extern "C" void kernel_launch(void* const* d_in, const int* in_sizes, int n_in,
                              void* d_out, int out_size, void* d_ws, size_t ws_size,
                              hipStream_t stream) {
    const float* x     = (const float*)d_in[0];
    const float* table = (const float*)d_in[1];
    const float* W0    = (const float*)d_in[2];
    const float* b0    = (const float*)d_in[3];
    const float* W1    = (const float*)d_in[4];
    const float* b1    = (const float*)d_in[5];
    const float* W2    = (const float*)d_in[6];
    const float* b2    = (const float*)d_in[7];
    float* out = (float*)d_out;

    const int N = in_sizes[0] / 3;

    Scales sc;
    const double pls = exp2(log2(2048.0 / 16.0) / 15.0);  // matches numpy double math
    for (int l = 0; l < NLV; ++l) sc.s[l] = (float)(16.0 * pow(pls, (double)l));

    const int block = 256;
    const int grid = (N + block - 1) / block;

    const size_t encB  = (size_t)N * 2u * NLV * sizeof(float);   // 128 MiB
    const size_t xsB   = (size_t)N * sizeof(float) * 4u;         //  16 MiB
    const size_t histB = (size_t)NBUCK * sizeof(unsigned);

    if (ws_size >= encB + xsB + histB) {
        float*    enc  = (float*)d_ws;
        vf4*      xs   = (vf4*)((char*)d_ws + encB);
        unsigned* hist = (unsigned*)((char*)d_ws + encB + xsB);

        zero_hist_kernel<<<(NBUCK + 255) / 256, block, 0, stream>>>(hist);
        hist_kernel<<<grid, block, 0, stream>>>(x, hist, N);
        scan_kernel<<<1, 1024, 0, stream>>>(hist);
        scatter_kernel<<<grid, block, 0, stream>>>(x, hist, xs, N);

        encode_coarse_kernel<<<grid, block, 0, stream>>>(xs, table, enc, N, sc);

        const int gridQ = (N + 1023) / 1024;   // 4 pts/thread fine kernels
        #define LAUNCH_FINE(L) \
            encode_fine_kernel<L><<<gridQ, block, 0, stream>>>( \
                xs, table + (size_t)(L) * T_SIZE * 2u, sc.s[(L)], \
                enc + (size_t)(L) * (size_t)N * 2u, N)
        LAUNCH_FINE(5);  LAUNCH_FINE(6);  LAUNCH_FINE(7);  LAUNCH_FINE(8);
        LAUNCH_FINE(9);  LAUNCH_FINE(10); LAUNCH_FINE(11); LAUNCH_FINE(12);
        LAUNCH_FINE(13); LAUNCH_FINE(14); LAUNCH_FINE(15);
        #undef LAUNCH_FINE

        const int gridM = (N + 511) / 512;     // 512 pts/block MLP
        mlp_kernel<<<gridM, block, 0, stream>>>(enc, xs, W0, b0, W1, b1, W2, b2, out, N);
    } else if (ws_size >= encB) {
        float* enc = (float*)d_ws;
        encode_coarse_unsorted_kernel<<<grid, block, 0, stream>>>(x, table, enc, N, sc);
        for (int l = 5; l < NLV; ++l) {
            encode_one_unsorted_kernel<<<grid, block, 0, stream>>>(
                x, table + (size_t)l * T_SIZE * 2u, sc.s[l],
                enc + (size_t)l * (size_t)N * 2u, N);
        }
        mlp_noperm_kernel<<<grid, block, 0, stream>>>(enc, W0, b0, W1, b1, W2, b2, out, N);
    } else {
        tcnn_fused_kernel<<<grid, block, 0, stream>>>(x, table, W0, b0, W1, b1, W2, b2,
                                                      out, N, sc);
    }
}

// Round 9
// 504.402 us; speedup vs baseline: 1.0991x; 1.0505x over previous
//
#include <hip/hip_runtime.h>
#include <math.h>

#define NLV 16
#define LOG2_T 19
#define T_SIZE (1u << LOG2_T)
#define T_MASK (T_SIZE - 1u)
#define P2 2654435761u
#define P3 805459861u
#define NBUCK 32768   // 32^3 Morton buckets

typedef float vf2 __attribute__((ext_vector_type(2)));
typedef float vf4 __attribute__((ext_vector_type(4)));

struct Scales { float s[NLV]; };

// ---------- Morton key (5 bits/axis) ----------
__device__ __forceinline__ unsigned mpart(unsigned v) {
    v = (v | (v << 8)) & 0x100Fu;
    v = (v | (v << 4)) & 0x10C3u;
    v = (v | (v << 2)) & 0x1249u;
    return v;
}
__device__ __forceinline__ unsigned mkey(float px, float py, float pz) {
    unsigned cx = (unsigned)(px * 32.f); cx = cx > 31u ? 31u : cx;
    unsigned cy = (unsigned)(py * 32.f); cy = cy > 31u ? 31u : cy;
    unsigned cz = (unsigned)(pz * 32.f); cz = cz > 31u ? 31u : cz;
    return mpart(cx) | (mpart(cy) << 1) | (mpart(cz) << 2);
}

// ---------- sort kernels (1 pt/thread: latency-bound, maximize wave count) ----------
__global__ __launch_bounds__(256) void zero_hist_kernel(unsigned* hist) {
    int i = blockIdx.x * 256 + threadIdx.x;
    if (i < NBUCK) hist[i] = 0u;
}

__global__ __launch_bounds__(256) void hist_kernel(
    const float* __restrict__ x, unsigned* __restrict__ hist, int N)
{
    const int i = blockIdx.x * 256 + threadIdx.x;
    if (i >= N) return;
    const float px = x[3 * (size_t)i + 0];
    const float py = x[3 * (size_t)i + 1];
    const float pz = x[3 * (size_t)i + 2];
    atomicAdd(&hist[mkey(px, py, pz)], 1u);
}

__global__ __launch_bounds__(1024) void scan_kernel(unsigned* hist) {
    __shared__ unsigned tot[1024];
    const int t = threadIdx.x;
    const unsigned base = (unsigned)t * 32u;
    unsigned loc[32];
    unsigned s = 0;
    #pragma unroll
    for (int k = 0; k < 32; ++k) { loc[k] = s; s += hist[base + k]; }
    tot[t] = s;
    __syncthreads();
    for (int off = 1; off < 1024; off <<= 1) {
        unsigned u = (t >= off) ? tot[t - off] : 0u;
        __syncthreads();
        tot[t] += u;
        __syncthreads();
    }
    const unsigned excl = tot[t] - s;
    #pragma unroll
    for (int k = 0; k < 32; ++k) hist[base + k] = excl + loc[k];
}

// One 16B record per point: {px,py,pz, bitcast(idx)} -> single line touch.
__global__ __launch_bounds__(256) void scatter_kernel(
    const float* __restrict__ x, unsigned* __restrict__ cursor,
    vf4* __restrict__ xs, int N)
{
    const int i = blockIdx.x * 256 + threadIdx.x;
    if (i >= N) return;
    const float px = x[3 * (size_t)i + 0];
    const float py = x[3 * (size_t)i + 1];
    const float pz = x[3 * (size_t)i + 2];
    const unsigned key = mkey(px, py, pz);
    const unsigned pos = atomicAdd(&cursor[key], 1u);
    vf4 v; v[0] = px; v[1] = py; v[2] = pz; v[3] = __int_as_float(i);
    xs[pos] = v;
}

// ---------- encode ----------
// PRIMES[0]==1 => h is linear in ix: h(ix+1) = h(ix)^1 when ix is even.
// The two x-corners then sit in one 16B-aligned entry pair -> one vf4 load
// fetches both (8 -> 4 L2 requests/point). Odd ix keeps the 8-load path.
// Both paths load identical floats and accumulate in identical c-order ->
// bit-identical results.
__device__ __forceinline__ void enc_level(
    float px, float py, float pz, float s, const float* __restrict__ tl,
    float& f0, float& f1)
{
    const float fx = px * s, fy = py * s, fz = pz * s;
    const float bx = floorf(fx), by = floorf(fy), bz = floorf(fz);
    const float rx = fx - bx, ry = fy - by, rz = fz - bz;
    const unsigned ix0 = (unsigned)bx, iy0 = (unsigned)by, iz0 = (unsigned)bz;
    const unsigned hy0 = iy0 * P2, hy1 = (iy0 + 1u) * P2;
    const unsigned hz0 = iz0 * P3, hz1 = (iz0 + 1u) * P3;
    const float wx0 = 1.f - rx, wy0 = 1.f - ry, wz0 = 1.f - rz;
    f0 = 0.f; f1 = 0.f;
    if (!(ix0 & 1u)) {
        float c0[8], c1[8];
        #pragma unroll
        for (int yz = 0; yz < 4; ++yz) {
            const unsigned r = ((yz & 2) ? hy1 : hy0) ^ ((yz & 1) ? hz1 : hz0);
            const unsigned h0 = (ix0 ^ r) & T_MASK;
            const vf4 q = *(const vf4*)(tl + 2u * (size_t)(h0 & ~1u));
            const bool odd = (h0 & 1u) != 0u;
            c0[yz]     = odd ? q[2] : q[0];   // corner (0,y,z) feature 0
            c1[yz]     = odd ? q[3] : q[1];   // corner (0,y,z) feature 1
            c0[4 + yz] = odd ? q[0] : q[2];   // corner (1,y,z) feature 0
            c1[4 + yz] = odd ? q[1] : q[3];   // corner (1,y,z) feature 1
        }
        #pragma unroll
        for (int c = 0; c < 8; ++c) {
            const float w = ((c & 4) ? rx : wx0) * ((c & 2) ? ry : wy0) * ((c & 1) ? rz : wz0);
            f0 += w * c0[(c >> 2) * 4 + (c & 3)];
            f1 += w * c1[(c >> 2) * 4 + (c & 3)];
        }
    } else {
        const unsigned hx0 = ix0, hx1 = ix0 + 1u;
        #pragma unroll
        for (int c = 0; c < 8; ++c) {
            unsigned h = ((c & 4) ? hx1 : hx0) ^ ((c & 2) ? hy1 : hy0) ^ ((c & 1) ? hz1 : hz0);
            h &= T_MASK;
            const vf2 f = *(const vf2*)(tl + 2u * (size_t)h);
            const float w = ((c & 4) ? rx : wx0) * ((c & 2) ? ry : wy0) * ((c & 1) ? rz : wz0);
            f0 += w * f[0];
            f1 += w * f[1];
        }
    }
}

// Levels 0..4 fused (working sets co-resident in L2, L1-friendly after sort).
__global__ __launch_bounds__(256) void encode_coarse_kernel(
    const vf4* __restrict__ xs, const float* __restrict__ table,
    float* __restrict__ enc, int N, Scales sc)
{
    int i = blockIdx.x * 256 + threadIdx.x;
    if (i >= N) return;
    const vf4 p = xs[i];
    #pragma unroll
    for (int l = 0; l < 5; ++l) {
        float f0, f1;
        enc_level(p[0], p[1], p[2], sc.s[l], table + (size_t)l * T_SIZE * 2u, f0, f1);
        vf2 v; v[0] = f0; v[1] = f1;
        *(vf2*)(enc + ((size_t)l * N + i) * 2u) = v;
    }
}

// One fine level per launch; 4 points/thread; LVL tag -> per-level rocprof rows.
template<int LVL>
__global__ __launch_bounds__(256) void encode_fine_kernel(
    const vf4* __restrict__ xs, const float* __restrict__ tl, float s,
    float* __restrict__ encl, int N)
{
    const int i0 = blockIdx.x * 1024 + threadIdx.x;
    #pragma unroll
    for (int k = 0; k < 4; ++k) {
        const int i = i0 + k * 256;
        if (i < N) {
            const vf4 p = xs[i];
            float f0, f1;
            enc_level(p[0], p[1], p[2], s, tl, f0, f1);
            vf2 v; v[0] = f0; v[1] = f1;
            *(vf2*)(encl + (size_t)i * 2u) = v;
        }
    }
}

// ---------- MLP: 512 pts/block in two 256-pt halves (17 KB LDS -> 8 blocks/CU),
// float2-pair accumulation, LDS-staged cooperative NT store ----------
__global__ __launch_bounds__(256) void mlp_kernel(
    const float* __restrict__ enc, const vf4* __restrict__ xs,
    const float* __restrict__ W0, const float* __restrict__ b0,
    const float* __restrict__ W1, const float* __restrict__ b1,
    const float* __restrict__ W2, const float* __restrict__ b2,
    float* __restrict__ out, int N)
{
    __shared__ float st[256 * 17];   // 17408 B
    const int base = blockIdx.x * 512;
    const int t = threadIdx.x;
    const float* xsf = (const float*)xs;

    #pragma unroll
    for (int q = 0; q < 2; ++q) {
        if (q) __syncthreads();              // st reuse hazard (uniform branch)
        const int i = base + q * 256 + t;
        if (i < N) {
            vf2 e2[16];
            #pragma unroll
            for (int l = 0; l < NLV; ++l)
                e2[l] = *(const vf2*)(enc + ((size_t)l * N + i) * 2u);

            vf2 a0v[8];
            #pragma unroll
            for (int j = 0; j < 16; ++j) {
                vf2 acc = {0.f, 0.f};
                #pragma unroll
                for (int l = 0; l < 16; ++l)
                    acc += e2[l] * *(const vf2*)(W0 + j * 32 + 2 * l);
                a0v[j >> 1][j & 1] = fmaxf(b0[j] + acc[0] + acc[1], 0.f);
            }
            vf2 a1v[8];
            #pragma unroll
            for (int j = 0; j < 16; ++j) {
                vf2 acc = {0.f, 0.f};
                #pragma unroll
                for (int k = 0; k < 8; ++k)
                    acc += a0v[k] * *(const vf2*)(W1 + j * 16 + 2 * k);
                a1v[j >> 1][j & 1] = fmaxf(b1[j] + acc[0] + acc[1], 0.f);
            }
            #pragma unroll
            for (int j = 0; j < 16; ++j) {
                vf2 acc = {0.f, 0.f};
                #pragma unroll
                for (int k = 0; k < 8; ++k)
                    acc += a1v[k] * *(const vf2*)(W2 + j * 16 + 2 * k);
                st[t * 17 + j] = b2[j] + acc[0] + acc[1];
            }
        }
        __syncthreads();

        // 4 lanes per point; the 4 x 16B quarters of each output line coalesce
        // into one full-line NT write (no L2 allocation, out is never re-read).
        const int c = t & 3;
        #pragma unroll
        for (int w = 0; w < 4; ++w) {
            const int p = (t >> 2) + w * 64;          // local row 0..255
            const int gi = base + q * 256 + p;
            if (gi < N) {
                const int dst = __float_as_int(xsf[4 * (size_t)gi + 3]);
                const vf4 v = *(const vf4*)&st[p * 17 + 4 * c];
                __builtin_nontemporal_store(v, (vf4*)(out + 16 * (size_t)dst + 4 * c));
            }
        }
    }
}

// ---------- fallback paths ----------
__global__ __launch_bounds__(256) void encode_coarse_unsorted_kernel(
    const float* __restrict__ x, const float* __restrict__ table,
    float* __restrict__ enc, int N, Scales sc)
{
    int i = blockIdx.x * 256 + threadIdx.x;
    if (i >= N) return;
    const float px = x[3 * (size_t)i + 0];
    const float py = x[3 * (size_t)i + 1];
    const float pz = x[3 * (size_t)i + 2];
    #pragma unroll
    for (int l = 0; l < 5; ++l) {
        float f0, f1;
        enc_level(px, py, pz, sc.s[l], table + (size_t)l * T_SIZE * 2u, f0, f1);
        vf2 v; v[0] = f0; v[1] = f1;
        *(vf2*)(enc + ((size_t)l * N + i) * 2u) = v;
    }
}
__global__ __launch_bounds__(256) void encode_one_unsorted_kernel(
    const float* __restrict__ x, const float* __restrict__ tl, float s,
    float* __restrict__ encl, int N)
{
    int i = blockIdx.x * 256 + threadIdx.x;
    if (i >= N) return;
    const float px = x[3 * (size_t)i + 0];
    const float py = x[3 * (size_t)i + 1];
    const float pz = x[3 * (size_t)i + 2];
    float f0, f1;
    enc_level(px, py, pz, s, tl, f0, f1);
    vf2 v; v[0] = f0; v[1] = f1;
    *(vf2*)(encl + (size_t)i * 2u) = v;
}
__global__ __launch_bounds__(256) void mlp_noperm_kernel(
    const float* __restrict__ enc,
    const float* __restrict__ W0, const float* __restrict__ b0,
    const float* __restrict__ W1, const float* __restrict__ b1,
    const float* __restrict__ W2, const float* __restrict__ b2,
    float* __restrict__ out, int N)
{
    int i = blockIdx.x * 256 + threadIdx.x;
    if (i >= N) return;
    float e[32];
    #pragma unroll
    for (int l = 0; l < NLV; ++l) {
        vf2 v = *(const vf2*)(enc + ((size_t)l * N + i) * 2u);
        e[2 * l + 0] = v[0];
        e[2 * l + 1] = v[1];
    }
    float a0[16];
    #pragma unroll
    for (int j = 0; j < 16; ++j) {
        float s = b0[j];
        #pragma unroll
        for (int k = 0; k < 32; ++k) s += e[k] * W0[j * 32 + k];
        a0[j] = fmaxf(s, 0.f);
    }
    float a1[16];
    #pragma unroll
    for (int j = 0; j < 16; ++j) {
        float s = b1[j];
        #pragma unroll
        for (int k = 0; k < 16; ++k) s += a0[k] * W1[j * 16 + k];
        a1[j] = fmaxf(s, 0.f);
    }
    #pragma unroll
    for (int j = 0; j < 16; ++j) {
        float s = b2[j];
        #pragma unroll
        for (int k = 0; k < 16; ++k) s += a1[k] * W2[j * 16 + k];
        out[16 * (size_t)i + j] = s;
    }
}
__global__ __launch_bounds__(256) void tcnn_fused_kernel(
    const float* __restrict__ x, const float* __restrict__ table,
    const float* __restrict__ W0, const float* __restrict__ b0,
    const float* __restrict__ W1, const float* __restrict__ b1,
    const float* __restrict__ W2, const float* __restrict__ b2,
    float* __restrict__ out, int N, Scales sc)
{
    int i = blockIdx.x * blockDim.x + threadIdx.x;
    if (i >= N) return;
    const float px = x[3 * (size_t)i + 0];
    const float py = x[3 * (size_t)i + 1];
    const float pz = x[3 * (size_t)i + 2];
    float e[32];
    #pragma unroll
    for (int l = 0; l < NLV; ++l) {
        float f0, f1;
        enc_level(px, py, pz, sc.s[l], table + (size_t)l * T_SIZE * 2u, f0, f1);
        e[2 * l] = f0; e[2 * l + 1] = f1;
    }
    float a0[16];
    #pragma unroll
    for (int j = 0; j < 16; ++j) {
        float s = b0[j];
        #pragma unroll
        for (int k = 0; k < 32; ++k) s += e[k] * W0[j * 32 + k];
        a0[j] = fmaxf(s, 0.f);
    }
    float a1[16];
    #pragma unroll
    for (int j = 0; j < 16; ++j) {
        float s = b1[j];
        #pragma unroll
        for (int k = 0; k < 16; ++k) s += a0[k] * W1[j * 16 + k];
        a1[j] = fmaxf(s, 0.f);
    }
    #pragma unroll
    for (int j = 0; j < 16; ++j) {
        float s = b2[j];
        #pragma unroll
        for (int k = 0; k < 16; ++k) s += a1[k] * W2[j * 16 + k];
        out[16 * (size_t)i + j] = s;
    }
}

extern "C" void kernel_launch(void* const* d_in, const int* in_sizes, int n_in,
                              void* d_out, int out_size, void* d_ws, size_t ws_size,
                              hipStream_t stream) {
    const float* x     = (const float*)d_in[0];
    const float* table = (const float*)d_in[1];
    const float* W0    = (const float*)d_in[2];
    const float* b0    = (const float*)d_in[3];
    const float* W1    = (const float*)d_in[4];
    const float* b1    = (const float*)d_in[5];
    const float* W2    = (const float*)d_in[6];
    const float* b2    = (const float*)d_in[7];
    float* out = (float*)d_out;

    const int N = in_sizes[0] / 3;

    Scales sc;
    const double pls = exp2(log2(2048.0 / 16.0) / 15.0);  // matches numpy double math
    for (int l = 0; l < NLV; ++l) sc.s[l] = (float)(16.0 * pow(pls, (double)l));

    const int block = 256;
    const int grid = (N + block - 1) / block;

    const size_t encB  = (size_t)N * 2u * NLV * sizeof(float);   // 128 MiB
    const size_t xsB   = (size_t)N * sizeof(float) * 4u;         //  16 MiB
    const size_t histB = (size_t)NBUCK * sizeof(unsigned);

    if (ws_size >= encB + xsB + histB) {
        float*    enc  = (float*)d_ws;
        vf4*      xs   = (vf4*)((char*)d_ws + encB);
        unsigned* hist = (unsigned*)((char*)d_ws + encB + xsB);

        zero_hist_kernel<<<(NBUCK + 255) / 256, block, 0, stream>>>(hist);
        hist_kernel<<<grid, block, 0, stream>>>(x, hist, N);
        scan_kernel<<<1, 1024, 0, stream>>>(hist);
        scatter_kernel<<<grid, block, 0, stream>>>(x, hist, xs, N);

        encode_coarse_kernel<<<grid, block, 0, stream>>>(xs, table, enc, N, sc);

        const int gridQ = (N + 1023) / 1024;   // 4 pts/thread fine kernels
        #define LAUNCH_FINE(L) \
            encode_fine_kernel<L><<<gridQ, block, 0, stream>>>( \
                xs, table + (size_t)(L) * T_SIZE * 2u, sc.s[(L)], \
                enc + (size_t)(L) * (size_t)N * 2u, N)
        LAUNCH_FINE(5);  LAUNCH_FINE(6);  LAUNCH_FINE(7);  LAUNCH_FINE(8);
        LAUNCH_FINE(9);  LAUNCH_FINE(10); LAUNCH_FINE(11); LAUNCH_FINE(12);
        LAUNCH_FINE(13); LAUNCH_FINE(14); LAUNCH_FINE(15);
        #undef LAUNCH_FINE

        const int gridM = (N + 511) / 512;     // 512 pts/block MLP
        mlp_kernel<<<gridM, block, 0, stream>>>(enc, xs, W0, b0, W1, b1, W2, b2, out, N);
    } else if (ws_size >= encB) {
        float* enc = (float*)d_ws;
        encode_coarse_unsorted_kernel<<<grid, block, 0, stream>>>(x, table, enc, N, sc);
        for (int l = 5; l < NLV; ++l) {
            encode_one_unsorted_kernel<<<grid, block, 0, stream>>>(
                x, table + (size_t)l * T_SIZE * 2u, sc.s[l],
                enc + (size_t)l * (size_t)N * 2u, N);
        }
        mlp_noperm_kernel<<<grid, block, 0, stream>>>(enc, W0, b0, W1, b1, W2, b2, out, N);
    } else {
        tcnn_fused_kernel<<<grid, block, 0, stream>>>(x, table, W0, b0, W1, b1, W2, b2,
                                                      out, N, sc);
    }
}